// Round 1
// baseline (597.520 us; speedup 1.0000x reference)
//
#include <hip/hip_runtime.h>

// VGCN layer: out = relu(0.5*norm*Agg(norm*X@W^T) + 0.5*init*deg^-1 + 0.5*X)
// CSR-by-counting-sort to avoid float atomics; wave-per-node gather aggregate.

#define DIM 128

__global__ __launch_bounds__(256) void count_deg_k(const int* __restrict__ dst,
                                                   int* __restrict__ deg, int E) {
    int e = blockIdx.x * 256 + threadIdx.x;
    if (e < E) atomicAdd(&deg[dst[e]], 1);
}

__global__ __launch_bounds__(256) void block_sums_k(const int* __restrict__ deg,
                                                    int* __restrict__ bsums, int N) {
    __shared__ int sh[256];
    int i = blockIdx.x * 256 + threadIdx.x;
    sh[threadIdx.x] = (i < N) ? deg[i] : 0;
    __syncthreads();
    for (int off = 128; off > 0; off >>= 1) {
        if (threadIdx.x < off) sh[threadIdx.x] += sh[threadIdx.x + off];
        __syncthreads();
    }
    if (threadIdx.x == 0) bsums[blockIdx.x] = sh[0];
}

__global__ void scan_serial_k(int* bsums, int nb, int* offsets, int N) {
    // single thread: exclusive scan of block sums (nb ~ 391)
    int run = 0;
    for (int b = 0; b < nb; b++) { int t = bsums[b]; bsums[b] = run; run += t; }
    offsets[N] = run;   // == E
}

__global__ __launch_bounds__(256) void scan_write_k(const int* __restrict__ deg,
                                                    const int* __restrict__ bsums,
                                                    int* __restrict__ offsets, int N) {
    __shared__ int sh[256];
    int i = blockIdx.x * 256 + threadIdx.x;
    int v = (i < N) ? deg[i] : 0;
    sh[threadIdx.x] = v;
    __syncthreads();
    // Hillis-Steele inclusive scan
    for (int off = 1; off < 256; off <<= 1) {
        int t = (threadIdx.x >= (unsigned)off) ? sh[threadIdx.x - off] : 0;
        __syncthreads();
        sh[threadIdx.x] += t;
        __syncthreads();
    }
    if (i < N) offsets[i] = bsums[blockIdx.x] + sh[threadIdx.x] - v;  // exclusive
}

__global__ __launch_bounds__(256) void fill_sorted_k(const int* __restrict__ src,
                                                     const int* __restrict__ dst,
                                                     const int* __restrict__ offsets,
                                                     int* __restrict__ cursor,
                                                     int* __restrict__ sorted_src, int E) {
    int e = blockIdx.x * 256 + threadIdx.x;
    if (e < E) {
        int d = dst[e];
        int p = offsets[d] + atomicAdd(&cursor[d], 1);
        sorted_src[p] = src[e];
    }
}

// h_lin[n][j] = (sum_k feat[n][k] * W[j][k]) * deg[n]^-1/2
__global__ __launch_bounds__(256) void linear_k(const float* __restrict__ feat,
                                                const float* __restrict__ W,
                                                const int* __restrict__ deg,
                                                float* __restrict__ h_lin, int N) {
    __shared__ float WT[DIM][DIM + 1];  // +1 pad: conflict-free read (consec j) and write (stride 129)
    __shared__ float fsh[2][DIM];
    int tid = threadIdx.x;
    for (int l = tid; l < DIM * DIM; l += 256) {
        int j = l >> 7, k = l & 127;
        WT[k][j] = W[l];
    }
    __syncthreads();
    int r = tid >> 7;       // which of the 2 rows this thread computes
    int j = tid & 127;      // output column
    for (int base = blockIdx.x * 2; base < N; base += gridDim.x * 2) {
        int lrow = base + (tid >> 7);
        if (lrow < N) fsh[tid >> 7][tid & 127] = feat[(size_t)lrow * DIM + (tid & 127)];
        __syncthreads();
        int n = base + r;
        if (n < N) {
            float a0 = 0.f, a1 = 0.f, a2 = 0.f, a3 = 0.f;
            #pragma unroll
            for (int k = 0; k < DIM; k += 4) {
                a0 += fsh[r][k + 0] * WT[k + 0][j];
                a1 += fsh[r][k + 1] * WT[k + 1][j];
                a2 += fsh[r][k + 2] * WT[k + 2][j];
                a3 += fsh[r][k + 3] * WT[k + 3][j];
            }
            float acc = (a0 + a1) + (a2 + a3);
            float dg = (float)max(deg[n], 1);
            h_lin[(size_t)n * DIM + j] = acc * rsqrtf(dg);
        }
        __syncthreads();
    }
}

// one wave per node: gather-sum CSR segment, fuse norm + alpha-combine + relu
__global__ __launch_bounds__(256) void aggregate_k(const float* __restrict__ h_lin,
                                                   const int* __restrict__ offsets,
                                                   const int* __restrict__ sorted_src,
                                                   const int* __restrict__ deg,
                                                   const float* __restrict__ feat,
                                                   const float* __restrict__ init,
                                                   float* __restrict__ out, int N) {
    int wave = (blockIdx.x * 256 + threadIdx.x) >> 6;
    int lane = threadIdx.x & 63;
    if (wave >= N) return;
    int n = wave;
    int s0 = offsets[n], s1 = offsets[n + 1];
    const float2* hl2 = (const float2*)h_lin;
    float ax = 0.f, ay = 0.f;
    for (int i = s0; i < s1; i++) {
        int s = sorted_src[i];
        float2 v = hl2[s * (DIM / 2) + lane];
        ax += v.x; ay += v.y;
    }
    float dg = (float)max(deg[n], 1);
    float nrm = rsqrtf(dg);
    float nrm1 = 1.0f / dg;
    float2 fv = ((const float2*)feat)[(size_t)n * (DIM / 2) + lane];
    float2 iv = ((const float2*)init)[(size_t)n * (DIM / 2) + lane];
    float ox = 0.5f * (ax * nrm) + 0.5f * iv.x * nrm1 + 0.5f * fv.x;
    float oy = 0.5f * (ay * nrm) + 0.5f * iv.y * nrm1 + 0.5f * fv.y;
    ((float2*)out)[(size_t)n * (DIM / 2) + lane] = make_float2(fmaxf(ox, 0.f), fmaxf(oy, 0.f));
}

extern "C" void kernel_launch(void* const* d_in, const int* in_sizes, int n_in,
                              void* d_out, int out_size, void* d_ws, size_t ws_size,
                              hipStream_t stream) {
    const float* feat = (const float*)d_in[0];
    const float* init = (const float*)d_in[1];
    const float* W    = (const float*)d_in[2];
    const int*   src  = (const int*)d_in[3];
    const int*   dst  = (const int*)d_in[4];
    const int N = in_sizes[0] / DIM;
    const int E = in_sizes[3];
    float* out = (float*)d_out;

    // workspace layout
    char* ws = (char*)d_ws;
    size_t o_deg = 0;
    size_t o_cur = o_deg + (size_t)N * 4;
    size_t o_bs  = o_cur + (size_t)N * 4;                  // block sums (nb ints, nb <= 512)
    size_t o_off = o_bs + 2048;
    size_t o_srt = (o_off + (size_t)(N + 1) * 4 + 127) & ~(size_t)127;
    size_t o_hl  = (o_srt + (size_t)E * 4 + 511) & ~(size_t)511;
    int*   deg        = (int*)(ws + o_deg);
    int*   cursor     = (int*)(ws + o_cur);
    int*   bsums      = (int*)(ws + o_bs);
    int*   offsets    = (int*)(ws + o_off);
    int*   sorted_src = (int*)(ws + o_srt);
    float* h_lin      = (float*)(ws + o_hl);

    const int nb = (N + 255) / 256;
    const int eb = (E + 255) / 256;

    // zero deg + cursor + bsums
    hipMemsetAsync(ws, 0, o_off, stream);

    count_deg_k<<<eb, 256, 0, stream>>>(dst, deg, E);
    block_sums_k<<<nb, 256, 0, stream>>>(deg, bsums, N);
    scan_serial_k<<<1, 1, 0, stream>>>(bsums, nb, offsets, N);
    scan_write_k<<<nb, 256, 0, stream>>>(deg, bsums, offsets, N);
    fill_sorted_k<<<eb, 256, 0, stream>>>(src, dst, offsets, cursor, sorted_src, E);

    linear_k<<<2048, 256, 0, stream>>>(feat, W, deg, h_lin, N);

    int agg_blocks = (int)(((size_t)N * 64 + 255) / 256);
    aggregate_k<<<agg_blocks, 256, 0, stream>>>(h_lin, offsets, sorted_src, deg,
                                                feat, init, out, N);
}

// Round 2
// 424.421 us; speedup vs baseline: 1.4078x; 1.4078x over previous
//
#include <hip/hip_runtime.h>

// VGCN layer, restructured:
//   agg[n]   = sum_{e: dst=n} norm[src] * X[src]          (bf16 gather-sum, CSR)
//   out[n]   = relu(0.5*norm[n]*(agg[n] @ W^T) + 0.5*init[n]/deg[n] + 0.5*X[n])
// Linear commutes with per-row scaling and segment_sum, so GEMM runs once on
// the aggregated features with a fused epilogue (bf16 MFMA 16x16x32).

#define DIM 128

typedef __attribute__((ext_vector_type(8))) short short8v;   // 8 bf16 (4 VGPRs)
typedef __attribute__((ext_vector_type(4))) float f32x4;     // MFMA acc

static __device__ __forceinline__ unsigned short f2b(float f) {
    unsigned u = __float_as_uint(f);
    unsigned r = (u >> 16) & 1;          // round-to-nearest-even
    u += 0x7fffu + r;
    return (unsigned short)(u >> 16);
}

__global__ __launch_bounds__(256) void count_deg_k(const int* __restrict__ dst,
                                                   int* __restrict__ deg, int E) {
    int e = blockIdx.x * 256 + threadIdx.x;
    if (e < E) atomicAdd(&deg[dst[e]], 1);
}

__global__ __launch_bounds__(256) void block_sums_k(const int* __restrict__ deg,
                                                    int* __restrict__ bsums, int N) {
    __shared__ int sh[256];
    int i = blockIdx.x * 256 + threadIdx.x;
    sh[threadIdx.x] = (i < N) ? deg[i] : 0;
    __syncthreads();
    for (int off = 128; off > 0; off >>= 1) {
        if (threadIdx.x < off) sh[threadIdx.x] += sh[threadIdx.x + off];
        __syncthreads();
    }
    if (threadIdx.x == 0) bsums[blockIdx.x] = sh[0];
}

__global__ void scan_serial_k(int* bsums, int nb, int* offsets, int N) {
    int run = 0;
    for (int b = 0; b < nb; b++) { int t = bsums[b]; bsums[b] = run; run += t; }
    offsets[N] = run;   // == E
}

__global__ __launch_bounds__(256) void scan_write_k(const int* __restrict__ deg,
                                                    const int* __restrict__ bsums,
                                                    int* __restrict__ offsets, int N) {
    __shared__ int sh[256];
    int i = blockIdx.x * 256 + threadIdx.x;
    int v = (i < N) ? deg[i] : 0;
    sh[threadIdx.x] = v;
    __syncthreads();
    for (int off = 1; off < 256; off <<= 1) {
        int t = (threadIdx.x >= (unsigned)off) ? sh[threadIdx.x - off] : 0;
        __syncthreads();
        sh[threadIdx.x] += t;
        __syncthreads();
    }
    if (i < N) offsets[i] = bsums[blockIdx.x] + sh[threadIdx.x] - v;  // exclusive
}

__global__ __launch_bounds__(256) void fill_sorted_k(const int* __restrict__ src,
                                                     const int* __restrict__ dst,
                                                     const int* __restrict__ offsets,
                                                     int* __restrict__ cursor,
                                                     int* __restrict__ sorted_src, int E) {
    int e = blockIdx.x * 256 + threadIdx.x;
    if (e < E) {
        int d = dst[e];
        int p = offsets[d] + atomicAdd(&cursor[d], 1);
        sorted_src[p] = src[e];
    }
}

// W (fp32 row-major [j][k]) -> bf16
__global__ __launch_bounds__(256) void prep_w_k(const float* __restrict__ W,
                                                unsigned short* __restrict__ wb) {
    int i = blockIdx.x * 256 + threadIdx.x;
    if (i < DIM * DIM) wb[i] = f2b(W[i]);
}

// feat_s[n][k] = bf16(norm[n] * feat[n][k]); one thread per 4 elems
__global__ __launch_bounds__(256) void prescale_k(const float* __restrict__ feat,
                                                  const int* __restrict__ offsets,
                                                  unsigned short* __restrict__ feat_s,
                                                  int N) {
    int idx = blockIdx.x * 256 + threadIdx.x;
    int total = N * (DIM / 4);
    if (idx >= total) return;
    int n = idx >> 5;                      // /(DIM/4)
    int dgi = offsets[n + 1] - offsets[n];
    float dg = (float)(dgi < 1 ? 1 : dgi);
    float nrm = rsqrtf(dg);
    float4 f = ((const float4*)feat)[idx];
    unsigned lo = (unsigned)f2b(f.x * nrm) | ((unsigned)f2b(f.y * nrm) << 16);
    unsigned hi = (unsigned)f2b(f.z * nrm) | ((unsigned)f2b(f.w * nrm) << 16);
    ((uint2*)feat_s)[idx] = make_uint2(lo, hi);
}

// one wave per node: gather-sum bf16 rows, fp32 accumulate, bf16 out
__global__ __launch_bounds__(256) void aggregate_k(const unsigned short* __restrict__ feat_s,
                                                   const int* __restrict__ offsets,
                                                   const int* __restrict__ sorted_src,
                                                   unsigned short* __restrict__ agg, int N) {
    int wave = (blockIdx.x * 256 + threadIdx.x) >> 6;
    int lane = threadIdx.x & 63;
    if (wave >= N) return;
    int s0 = offsets[wave], s1 = offsets[wave + 1];
    float ax = 0.f, ay = 0.f;
    for (int i = s0; i < s1; i++) {
        int s = sorted_src[i];
        unsigned v = *(const unsigned*)(feat_s + (size_t)s * DIM + lane * 2);
        ax += __uint_as_float(v << 16);          // element 2*lane
        ay += __uint_as_float(v & 0xffff0000u);  // element 2*lane+1
    }
    unsigned p = (unsigned)f2b(ax) | ((unsigned)f2b(ay) << 16);
    *(unsigned*)(agg + (size_t)wave * DIM + lane * 2) = p;
}

// GEMM: out = relu(0.5*norm*(agg @ W^T) + 0.5*init/deg + 0.5*feat)
// block = 256 thr = 4 waves; wave computes 32 rows x 128 cols; block = 128 rows.
__global__ __launch_bounds__(256) void gemm_ep_k(const unsigned short* __restrict__ agg,
                                                 const unsigned short* __restrict__ wb,
                                                 const int* __restrict__ offsets,
                                                 const float* __restrict__ feat,
                                                 const float* __restrict__ init,
                                                 float* __restrict__ out, int N) {
    int wid = threadIdx.x >> 6;
    int lane = threadIdx.x & 63;
    int row16 = lane & 15;
    int kb = lane >> 4;                 // 0..3, k block of 8
    int base_m = blockIdx.x * 128 + wid * 32;

    // A fragments: 2 m-tiles x 4 k-steps, 16B contiguous loads from agg rows
    short8v afr[2][4];
    #pragma unroll
    for (int mt = 0; mt < 2; mt++) {
        int m = base_m + mt * 16 + row16;
        if (m >= N) m = N - 1;          // clamp; store is masked
        const short8v* ap = (const short8v*)(agg + (size_t)m * DIM);
        #pragma unroll
        for (int ks = 0; ks < 4; ks++) afr[mt][ks] = ap[ks * 4 + kb];
    }

    f32x4 acc[2][8] = {};
    #pragma unroll
    for (int ct = 0; ct < 8; ct++) {
        int j = ct * 16 + row16;        // B col = W row (B = W^T)
        const short8v* bp = (const short8v*)(wb + (size_t)j * DIM);
        #pragma unroll
        for (int ks = 0; ks < 4; ks++) {
            short8v bfr = bp[ks * 4 + kb];
            acc[0][ct] = __builtin_amdgcn_mfma_f32_16x16x32_bf16(afr[0][ks], bfr, acc[0][ct], 0, 0, 0);
            acc[1][ct] = __builtin_amdgcn_mfma_f32_16x16x32_bf16(afr[1][ks], bfr, acc[1][ct], 0, 0, 0);
        }
    }

    // epilogue: D layout col=lane&15, row=(lane>>4)*4+reg
    #pragma unroll
    for (int mt = 0; mt < 2; mt++) {
        int m0 = base_m + mt * 16 + (lane >> 4) * 4;
        #pragma unroll
        for (int r = 0; r < 4; r++) {
            int m = m0 + r;
            if (m >= N) continue;
            int dgi = offsets[m + 1] - offsets[m];
            float dg = (float)(dgi < 1 ? 1 : dgi);
            float nrm = rsqrtf(dg);
            float n1 = 1.0f / dg;
            #pragma unroll
            for (int ct = 0; ct < 8; ct++) {
                int j = ct * 16 + row16;
                float o = 0.5f * nrm * acc[mt][ct][r]
                        + 0.5f * n1 * init[(size_t)m * DIM + j]
                        + 0.5f * feat[(size_t)m * DIM + j];
                out[(size_t)m * DIM + j] = fmaxf(o, 0.f);
            }
        }
    }
}

extern "C" void kernel_launch(void* const* d_in, const int* in_sizes, int n_in,
                              void* d_out, int out_size, void* d_ws, size_t ws_size,
                              hipStream_t stream) {
    const float* feat = (const float*)d_in[0];
    const float* init = (const float*)d_in[1];
    const float* W    = (const float*)d_in[2];
    const int*   src  = (const int*)d_in[3];
    const int*   dst  = (const int*)d_in[4];
    const int N = in_sizes[0] / DIM;
    const int E = in_sizes[3];
    float* out = (float*)d_out;

    // workspace layout (deg doubles as fill cursor after scan; deg derived
    // later as offsets[n+1]-offsets[n])
    char* ws = (char*)d_ws;
    size_t o_deg = 0;
    size_t o_bs  = o_deg + (size_t)N * 4;
    size_t o_off = o_bs + 2048;
    size_t o_srt = (o_off + (size_t)(N + 1) * 4 + 127) & ~(size_t)127;
    size_t o_fs  = (o_srt + (size_t)E * 4 + 511) & ~(size_t)511;
    size_t o_agg = o_fs + (size_t)N * DIM * 2;
    size_t o_w   = o_agg + (size_t)N * DIM * 2;
    int*            deg        = (int*)(ws + o_deg);   // later reused as cursor
    int*            bsums      = (int*)(ws + o_bs);
    int*            offsets    = (int*)(ws + o_off);
    int*            sorted_src = (int*)(ws + o_srt);
    unsigned short* feat_s     = (unsigned short*)(ws + o_fs);
    unsigned short* agg        = (unsigned short*)(ws + o_agg);
    unsigned short* wb         = (unsigned short*)(ws + o_w);

    const int nb = (N + 255) / 256;
    const int eb = (E + 255) / 256;

    hipMemsetAsync(ws, 0, o_off, stream);                         // deg + bsums
    count_deg_k<<<eb, 256, 0, stream>>>(dst, deg, E);
    block_sums_k<<<nb, 256, 0, stream>>>(deg, bsums, N);
    scan_serial_k<<<1, 1, 0, stream>>>(bsums, nb, offsets, N);
    scan_write_k<<<nb, 256, 0, stream>>>(deg, bsums, offsets, N);
    hipMemsetAsync(deg, 0, (size_t)N * 4, stream);                // reuse as cursor
    fill_sorted_k<<<eb, 256, 0, stream>>>(src, dst, offsets, deg, sorted_src, E);

    prep_w_k<<<(DIM * DIM + 255) / 256, 256, 0, stream>>>(W, wb);
    prescale_k<<<(N * (DIM / 4) + 255) / 256, 256, 0, stream>>>(feat, offsets, feat_s, N);
    aggregate_k<<<(int)(((size_t)N * 64 + 255) / 256), 256, 0, stream>>>(
        feat_s, offsets, sorted_src, agg, N);
    gemm_ep_k<<<(N + 127) / 128, 256, 0, stream>>>(agg, wb, offsets, feat, init, out, N);
}

// Round 3
// 289.876 us; speedup vs baseline: 2.0613x; 1.4641x over previous
//
#include <hip/hip_runtime.h>

// VGCN layer, restructured:
//   agg[n]   = sum_{e: dst=n} norm[src] * X[src]          (bf16 gather-sum, CSR)
//   out[n]   = relu(0.5*norm[n]*(agg[n] @ W^T) + 0.5*init[n]/deg[n] + 0.5*X[n])
// Linear commutes with per-row scaling and segment_sum, so GEMM runs once on
// the aggregated features with a fused epilogue (bf16 MFMA 16x16x32).
// R3: pipelined gather (8 idx batch -> 8 in-flight row gathers); 1-block scan.

#define DIM 128

typedef __attribute__((ext_vector_type(8))) short short8v;   // 8 bf16 (4 VGPRs)
typedef __attribute__((ext_vector_type(4))) float f32x4;     // MFMA acc

static __device__ __forceinline__ unsigned short f2b(float f) {
    unsigned u = __float_as_uint(f);
    unsigned r = (u >> 16) & 1;          // round-to-nearest-even
    u += 0x7fffu + r;
    return (unsigned short)(u >> 16);
}

__global__ __launch_bounds__(256) void count_deg_k(const int* __restrict__ dst,
                                                   int* __restrict__ deg, int E) {
    int e = blockIdx.x * 256 + threadIdx.x;
    if (e < E) atomicAdd(&deg[dst[e]], 1);
}

__global__ __launch_bounds__(256) void block_sums_k(const int* __restrict__ deg,
                                                    int* __restrict__ bsums, int N) {
    __shared__ int sh[256];
    int i = blockIdx.x * 256 + threadIdx.x;
    sh[threadIdx.x] = (i < N) ? deg[i] : 0;
    __syncthreads();
    for (int off = 128; off > 0; off >>= 1) {
        if (threadIdx.x < off) sh[threadIdx.x] += sh[threadIdx.x + off];
        __syncthreads();
    }
    if (threadIdx.x == 0) bsums[blockIdx.x] = sh[0];
}

// one block of 512 threads: exclusive scan of nb (<=512) block sums
__global__ __launch_bounds__(512) void scan_bsums_k(int* __restrict__ bsums, int nb,
                                                    int* __restrict__ offsets, int N) {
    __shared__ int sh[512];
    int t = threadIdx.x;
    int v = (t < nb) ? bsums[t] : 0;
    sh[t] = v;
    __syncthreads();
    for (int off = 1; off < 512; off <<= 1) {
        int u = (t >= off) ? sh[t - off] : 0;
        __syncthreads();
        sh[t] += u;
        __syncthreads();
    }
    if (t < nb) bsums[t] = sh[t] - v;          // exclusive
    if (t == nb - 1) offsets[N] = sh[t];       // total == E
}

__global__ __launch_bounds__(256) void scan_write_k(const int* __restrict__ deg,
                                                    const int* __restrict__ bsums,
                                                    int* __restrict__ offsets, int N) {
    __shared__ int sh[256];
    int i = blockIdx.x * 256 + threadIdx.x;
    int v = (i < N) ? deg[i] : 0;
    sh[threadIdx.x] = v;
    __syncthreads();
    for (int off = 1; off < 256; off <<= 1) {
        int t = (threadIdx.x >= (unsigned)off) ? sh[threadIdx.x - off] : 0;
        __syncthreads();
        sh[threadIdx.x] += t;
        __syncthreads();
    }
    if (i < N) offsets[i] = bsums[blockIdx.x] + sh[threadIdx.x] - v;  // exclusive
}

__global__ __launch_bounds__(256) void fill_sorted_k(const int* __restrict__ src,
                                                     const int* __restrict__ dst,
                                                     const int* __restrict__ offsets,
                                                     int* __restrict__ cursor,
                                                     int* __restrict__ sorted_src, int E) {
    int e = blockIdx.x * 256 + threadIdx.x;
    if (e < E) {
        int d = dst[e];
        int p = offsets[d] + atomicAdd(&cursor[d], 1);
        sorted_src[p] = src[e];
    }
}

// W (fp32 row-major [j][k]) -> bf16
__global__ __launch_bounds__(256) void prep_w_k(const float* __restrict__ W,
                                                unsigned short* __restrict__ wb) {
    int i = blockIdx.x * 256 + threadIdx.x;
    if (i < DIM * DIM) wb[i] = f2b(W[i]);
}

// feat_s[n][k] = bf16(norm[n] * feat[n][k]); one thread per 4 elems
__global__ __launch_bounds__(256) void prescale_k(const float* __restrict__ feat,
                                                  const int* __restrict__ offsets,
                                                  unsigned short* __restrict__ feat_s,
                                                  int N) {
    int idx = blockIdx.x * 256 + threadIdx.x;
    int total = N * (DIM / 4);
    if (idx >= total) return;
    int n = idx >> 5;                      // /(DIM/4)
    int dgi = offsets[n + 1] - offsets[n];
    float dg = (float)(dgi < 1 ? 1 : dgi);
    float nrm = rsqrtf(dg);
    float4 f = ((const float4*)feat)[idx];
    unsigned lo = (unsigned)f2b(f.x * nrm) | ((unsigned)f2b(f.y * nrm) << 16);
    unsigned hi = (unsigned)f2b(f.z * nrm) | ((unsigned)f2b(f.w * nrm) << 16);
    ((uint2*)feat_s)[idx] = make_uint2(lo, hi);
}

// one wave per node: gather-sum bf16 rows with 8-deep MLP pipelining
__global__ __launch_bounds__(256) void aggregate_k(const unsigned short* __restrict__ feat_s,
                                                   const int* __restrict__ offsets,
                                                   const int* __restrict__ sorted_src,
                                                   unsigned short* __restrict__ agg, int N) {
    int wave = (blockIdx.x * 256 + threadIdx.x) >> 6;
    int lane = threadIdx.x & 63;
    if (wave >= N) return;
    int s0 = __builtin_amdgcn_readfirstlane(offsets[wave]);
    int s1 = __builtin_amdgcn_readfirstlane(offsets[wave + 1]);
    float ax = 0.f, ay = 0.f;
    int i = s0;
    // 8-deep batches: idx loads issue together, then 8 independent gathers
    for (; i + 8 <= s1; i += 8) {
        int idx[8];
        #pragma unroll
        for (int k = 0; k < 8; k++) idx[k] = sorted_src[i + k];
        unsigned v[8];
        #pragma unroll
        for (int k = 0; k < 8; k++)
            v[k] = *(const unsigned*)(feat_s + (size_t)idx[k] * DIM + lane * 2);
        #pragma unroll
        for (int k = 0; k < 8; k++) {
            ax += __uint_as_float(v[k] << 16);
            ay += __uint_as_float(v[k] & 0xffff0000u);
        }
    }
    for (; i + 2 <= s1; i += 2) {
        int i0 = sorted_src[i], i1 = sorted_src[i + 1];
        unsigned v0 = *(const unsigned*)(feat_s + (size_t)i0 * DIM + lane * 2);
        unsigned v1 = *(const unsigned*)(feat_s + (size_t)i1 * DIM + lane * 2);
        ax += __uint_as_float(v0 << 16) + __uint_as_float(v1 << 16);
        ay += __uint_as_float(v0 & 0xffff0000u) + __uint_as_float(v1 & 0xffff0000u);
    }
    if (i < s1) {
        int i0 = sorted_src[i];
        unsigned v0 = *(const unsigned*)(feat_s + (size_t)i0 * DIM + lane * 2);
        ax += __uint_as_float(v0 << 16);
        ay += __uint_as_float(v0 & 0xffff0000u);
    }
    unsigned p = (unsigned)f2b(ax) | ((unsigned)f2b(ay) << 16);
    *(unsigned*)(agg + (size_t)wave * DIM + lane * 2) = p;
}

// GEMM: out = relu(0.5*norm*(agg @ W^T) + 0.5*init/deg + 0.5*feat)
// block = 256 thr = 4 waves; wave computes 32 rows x 128 cols; block = 128 rows.
__global__ __launch_bounds__(256) void gemm_ep_k(const unsigned short* __restrict__ agg,
                                                 const unsigned short* __restrict__ wb,
                                                 const int* __restrict__ offsets,
                                                 const float* __restrict__ feat,
                                                 const float* __restrict__ init,
                                                 float* __restrict__ out, int N) {
    int wid = threadIdx.x >> 6;
    int lane = threadIdx.x & 63;
    int row16 = lane & 15;
    int kb = lane >> 4;                 // 0..3, k block of 8
    int base_m = blockIdx.x * 128 + wid * 32;

    short8v afr[2][4];
    #pragma unroll
    for (int mt = 0; mt < 2; mt++) {
        int m = base_m + mt * 16 + row16;
        if (m >= N) m = N - 1;          // clamp; store is masked
        const short8v* ap = (const short8v*)(agg + (size_t)m * DIM);
        #pragma unroll
        for (int ks = 0; ks < 4; ks++) afr[mt][ks] = ap[ks * 4 + kb];
    }

    f32x4 acc[2][8] = {};
    #pragma unroll
    for (int ct = 0; ct < 8; ct++) {
        int j = ct * 16 + row16;        // B col = W row (B = W^T)
        const short8v* bp = (const short8v*)(wb + (size_t)j * DIM);
        #pragma unroll
        for (int ks = 0; ks < 4; ks++) {
            short8v bfr = bp[ks * 4 + kb];
            acc[0][ct] = __builtin_amdgcn_mfma_f32_16x16x32_bf16(afr[0][ks], bfr, acc[0][ct], 0, 0, 0);
            acc[1][ct] = __builtin_amdgcn_mfma_f32_16x16x32_bf16(afr[1][ks], bfr, acc[1][ct], 0, 0, 0);
        }
    }

    // epilogue: D layout col=lane&15, row=(lane>>4)*4+reg
    #pragma unroll
    for (int mt = 0; mt < 2; mt++) {
        int m0 = base_m + mt * 16 + (lane >> 4) * 4;
        #pragma unroll
        for (int r = 0; r < 4; r++) {
            int m = m0 + r;
            if (m >= N) continue;
            int dgi = offsets[m + 1] - offsets[m];
            float dg = (float)(dgi < 1 ? 1 : dgi);
            float nrm = rsqrtf(dg);
            float n1 = 1.0f / dg;
            #pragma unroll
            for (int ct = 0; ct < 8; ct++) {
                int j = ct * 16 + row16;
                float o = 0.5f * nrm * acc[mt][ct][r]
                        + 0.5f * n1 * init[(size_t)m * DIM + j]
                        + 0.5f * feat[(size_t)m * DIM + j];
                out[(size_t)m * DIM + j] = fmaxf(o, 0.f);
            }
        }
    }
}

extern "C" void kernel_launch(void* const* d_in, const int* in_sizes, int n_in,
                              void* d_out, int out_size, void* d_ws, size_t ws_size,
                              hipStream_t stream) {
    const float* feat = (const float*)d_in[0];
    const float* init = (const float*)d_in[1];
    const float* W    = (const float*)d_in[2];
    const int*   src  = (const int*)d_in[3];
    const int*   dst  = (const int*)d_in[4];
    const int N = in_sizes[0] / DIM;
    const int E = in_sizes[3];
    float* out = (float*)d_out;

    char* ws = (char*)d_ws;
    size_t o_deg = 0;
    size_t o_bs  = o_deg + (size_t)N * 4;
    size_t o_off = o_bs + 2048;
    size_t o_srt = (o_off + (size_t)(N + 1) * 4 + 127) & ~(size_t)127;
    size_t o_fs  = (o_srt + (size_t)E * 4 + 511) & ~(size_t)511;
    size_t o_agg = o_fs + (size_t)N * DIM * 2;
    size_t o_w   = o_agg + (size_t)N * DIM * 2;
    int*            deg        = (int*)(ws + o_deg);   // later reused as cursor
    int*            bsums      = (int*)(ws + o_bs);
    int*            offsets    = (int*)(ws + o_off);
    int*            sorted_src = (int*)(ws + o_srt);
    unsigned short* feat_s     = (unsigned short*)(ws + o_fs);
    unsigned short* agg        = (unsigned short*)(ws + o_agg);
    unsigned short* wb         = (unsigned short*)(ws + o_w);

    const int nb = (N + 255) / 256;
    const int eb = (E + 255) / 256;

    hipMemsetAsync(ws, 0, o_off, stream);                         // deg + bsums
    count_deg_k<<<eb, 256, 0, stream>>>(dst, deg, E);
    block_sums_k<<<nb, 256, 0, stream>>>(deg, bsums, N);
    scan_bsums_k<<<1, 512, 0, stream>>>(bsums, nb, offsets, N);
    scan_write_k<<<nb, 256, 0, stream>>>(deg, bsums, offsets, N);
    hipMemsetAsync(deg, 0, (size_t)N * 4, stream);                // reuse as cursor
    fill_sorted_k<<<eb, 256, 0, stream>>>(src, dst, offsets, deg, sorted_src, E);

    prep_w_k<<<(DIM * DIM + 255) / 256, 256, 0, stream>>>(W, wb);
    prescale_k<<<(N * (DIM / 4) + 255) / 256, 256, 0, stream>>>(feat, offsets, feat_s, N);
    aggregate_k<<<(int)(((size_t)N * 64 + 255) / 256), 256, 0, stream>>>(
        feat_s, offsets, sorted_src, agg, N);
    gemm_ep_k<<<(N + 127) / 128, 256, 0, stream>>>(agg, wb, offsets, feat, init, out, N);
}

// Round 4
// 267.654 us; speedup vs baseline: 2.2324x; 1.0830x over previous
//
#include <hip/hip_runtime.h>

// VGCN layer, restructured:
//   agg[n]   = sum_{e: dst=n} norm[src] * X[src]          (bf16 gather-sum, CSR)
//   out[n]   = relu(0.5*norm[n]*(agg[n] @ W^T) + 0.5*init[n]/deg[n] + 0.5*X[n])
// R3: pipelined gather (8-deep); 1-block scan.
// R4: XCD-partitioned CSR fill — each XCD commits only its dst-range, so the
//     6.4MB scatter becomes 8x 800KB L2-resident scatters (write-combining
//     works; WRITE_SIZE was 107MB for a 6.4MB buffer before).

#define DIM 128

typedef __attribute__((ext_vector_type(8))) short short8v;   // 8 bf16 (4 VGPRs)
typedef __attribute__((ext_vector_type(4))) float f32x4;     // MFMA acc

static __device__ __forceinline__ unsigned short f2b(float f) {
    unsigned u = __float_as_uint(f);
    unsigned r = (u >> 16) & 1;          // round-to-nearest-even
    u += 0x7fffu + r;
    return (unsigned short)(u >> 16);
}

__global__ __launch_bounds__(256) void count_deg_k(const int* __restrict__ dst,
                                                   int* __restrict__ deg, int E) {
    int e = blockIdx.x * 256 + threadIdx.x;
    if (e < E) atomicAdd(&deg[dst[e]], 1);
}

__global__ __launch_bounds__(256) void block_sums_k(const int* __restrict__ deg,
                                                    int* __restrict__ bsums, int N) {
    __shared__ int sh[256];
    int i = blockIdx.x * 256 + threadIdx.x;
    sh[threadIdx.x] = (i < N) ? deg[i] : 0;
    __syncthreads();
    for (int off = 128; off > 0; off >>= 1) {
        if (threadIdx.x < off) sh[threadIdx.x] += sh[threadIdx.x + off];
        __syncthreads();
    }
    if (threadIdx.x == 0) bsums[blockIdx.x] = sh[0];
}

// one block of 512 threads: exclusive scan of nb (<=512) block sums
__global__ __launch_bounds__(512) void scan_bsums_k(int* __restrict__ bsums, int nb,
                                                    int* __restrict__ offsets, int N) {
    __shared__ int sh[512];
    int t = threadIdx.x;
    int v = (t < nb) ? bsums[t] : 0;
    sh[t] = v;
    __syncthreads();
    for (int off = 1; off < 512; off <<= 1) {
        int u = (t >= off) ? sh[t - off] : 0;
        __syncthreads();
        sh[t] += u;
        __syncthreads();
    }
    if (t < nb) bsums[t] = sh[t] - v;          // exclusive
    if (t == nb - 1) offsets[N] = sh[t];       // total == E
}

__global__ __launch_bounds__(256) void scan_write_k(const int* __restrict__ deg,
                                                    const int* __restrict__ bsums,
                                                    int* __restrict__ offsets, int N) {
    __shared__ int sh[256];
    int i = blockIdx.x * 256 + threadIdx.x;
    int v = (i < N) ? deg[i] : 0;
    sh[threadIdx.x] = v;
    __syncthreads();
    for (int off = 1; off < 256; off <<= 1) {
        int t = (threadIdx.x >= (unsigned)off) ? sh[threadIdx.x - off] : 0;
        __syncthreads();
        sh[threadIdx.x] += t;
        __syncthreads();
    }
    if (i < N) offsets[i] = bsums[blockIdx.x] + sh[threadIdx.x] - v;  // exclusive
}

// XCD-partitioned fill: part p = blockIdx&7 (round-robin XCD heuristic) owns
// nodes [p*npp, (p+1)*npp); its 256 blocks sweep the whole edge list and
// commit only matching edges. Writes stay in one XCD's L2 slice.
__global__ __launch_bounds__(256) void fill_sorted_xcd_k(const int* __restrict__ src,
                                                         const int* __restrict__ dst,
                                                         const int* __restrict__ offsets,
                                                         int* __restrict__ cursor,
                                                         int* __restrict__ sorted_src,
                                                         int E, int npp) {
    int part = blockIdx.x & 7;
    int q    = blockIdx.x >> 3;               // block index within part
    int nq   = gridDim.x >> 3;
    int lo = part * npp, hi = lo + npp;
    int stride = nq * 256;
    for (int e = q * 256 + threadIdx.x; e < E; e += stride) {
        int d = dst[e];
        if (d >= lo && d < hi) {
            int p = offsets[d] + atomicAdd(&cursor[d], 1);
            sorted_src[p] = src[e];
        }
    }
}

// W (fp32 row-major [j][k]) -> bf16
__global__ __launch_bounds__(256) void prep_w_k(const float* __restrict__ W,
                                                unsigned short* __restrict__ wb) {
    int i = blockIdx.x * 256 + threadIdx.x;
    if (i < DIM * DIM) wb[i] = f2b(W[i]);
}

// feat_s[n][k] = bf16(norm[n] * feat[n][k]); one thread per 4 elems
__global__ __launch_bounds__(256) void prescale_k(const float* __restrict__ feat,
                                                  const int* __restrict__ offsets,
                                                  unsigned short* __restrict__ feat_s,
                                                  int N) {
    int idx = blockIdx.x * 256 + threadIdx.x;
    int total = N * (DIM / 4);
    if (idx >= total) return;
    int n = idx >> 5;                      // /(DIM/4)
    int dgi = offsets[n + 1] - offsets[n];
    float dg = (float)(dgi < 1 ? 1 : dgi);
    float nrm = rsqrtf(dg);
    float4 f = ((const float4*)feat)[idx];
    unsigned lo = (unsigned)f2b(f.x * nrm) | ((unsigned)f2b(f.y * nrm) << 16);
    unsigned hi = (unsigned)f2b(f.z * nrm) | ((unsigned)f2b(f.w * nrm) << 16);
    ((uint2*)feat_s)[idx] = make_uint2(lo, hi);
}

// one wave per node: gather-sum bf16 rows with 8-deep MLP pipelining
__global__ __launch_bounds__(256) void aggregate_k(const unsigned short* __restrict__ feat_s,
                                                   const int* __restrict__ offsets,
                                                   const int* __restrict__ sorted_src,
                                                   unsigned short* __restrict__ agg, int N) {
    int wave = (blockIdx.x * 256 + threadIdx.x) >> 6;
    int lane = threadIdx.x & 63;
    if (wave >= N) return;
    int s0 = __builtin_amdgcn_readfirstlane(offsets[wave]);
    int s1 = __builtin_amdgcn_readfirstlane(offsets[wave + 1]);
    float ax = 0.f, ay = 0.f;
    int i = s0;
    for (; i + 8 <= s1; i += 8) {
        int idx[8];
        #pragma unroll
        for (int k = 0; k < 8; k++) idx[k] = sorted_src[i + k];
        unsigned v[8];
        #pragma unroll
        for (int k = 0; k < 8; k++)
            v[k] = *(const unsigned*)(feat_s + (size_t)idx[k] * DIM + lane * 2);
        #pragma unroll
        for (int k = 0; k < 8; k++) {
            ax += __uint_as_float(v[k] << 16);
            ay += __uint_as_float(v[k] & 0xffff0000u);
        }
    }
    for (; i + 2 <= s1; i += 2) {
        int i0 = sorted_src[i], i1 = sorted_src[i + 1];
        unsigned v0 = *(const unsigned*)(feat_s + (size_t)i0 * DIM + lane * 2);
        unsigned v1 = *(const unsigned*)(feat_s + (size_t)i1 * DIM + lane * 2);
        ax += __uint_as_float(v0 << 16) + __uint_as_float(v1 << 16);
        ay += __uint_as_float(v0 & 0xffff0000u) + __uint_as_float(v1 & 0xffff0000u);
    }
    if (i < s1) {
        int i0 = sorted_src[i];
        unsigned v0 = *(const unsigned*)(feat_s + (size_t)i0 * DIM + lane * 2);
        ax += __uint_as_float(v0 << 16);
        ay += __uint_as_float(v0 & 0xffff0000u);
    }
    unsigned p = (unsigned)f2b(ax) | ((unsigned)f2b(ay) << 16);
    *(unsigned*)(agg + (size_t)wave * DIM + lane * 2) = p;
}

// GEMM: out = relu(0.5*norm*(agg @ W^T) + 0.5*init/deg + 0.5*feat)
__global__ __launch_bounds__(256) void gemm_ep_k(const unsigned short* __restrict__ agg,
                                                 const unsigned short* __restrict__ wb,
                                                 const int* __restrict__ offsets,
                                                 const float* __restrict__ feat,
                                                 const float* __restrict__ init,
                                                 float* __restrict__ out, int N) {
    int wid = threadIdx.x >> 6;
    int lane = threadIdx.x & 63;
    int row16 = lane & 15;
    int kb = lane >> 4;                 // 0..3, k block of 8
    int base_m = blockIdx.x * 128 + wid * 32;

    short8v afr[2][4];
    #pragma unroll
    for (int mt = 0; mt < 2; mt++) {
        int m = base_m + mt * 16 + row16;
        if (m >= N) m = N - 1;          // clamp; store is masked
        const short8v* ap = (const short8v*)(agg + (size_t)m * DIM);
        #pragma unroll
        for (int ks = 0; ks < 4; ks++) afr[mt][ks] = ap[ks * 4 + kb];
    }

    f32x4 acc[2][8] = {};
    #pragma unroll
    for (int ct = 0; ct < 8; ct++) {
        int j = ct * 16 + row16;        // B col = W row (B = W^T)
        const short8v* bp = (const short8v*)(wb + (size_t)j * DIM);
        #pragma unroll
        for (int ks = 0; ks < 4; ks++) {
            short8v bfr = bp[ks * 4 + kb];
            acc[0][ct] = __builtin_amdgcn_mfma_f32_16x16x32_bf16(afr[0][ks], bfr, acc[0][ct], 0, 0, 0);
            acc[1][ct] = __builtin_amdgcn_mfma_f32_16x16x32_bf16(afr[1][ks], bfr, acc[1][ct], 0, 0, 0);
        }
    }

    // epilogue: D layout col=lane&15, row=(lane>>4)*4+reg
    #pragma unroll
    for (int mt = 0; mt < 2; mt++) {
        int m0 = base_m + mt * 16 + (lane >> 4) * 4;
        #pragma unroll
        for (int r = 0; r < 4; r++) {
            int m = m0 + r;
            if (m >= N) continue;
            int dgi = offsets[m + 1] - offsets[m];
            float dg = (float)(dgi < 1 ? 1 : dgi);
            float nrm = rsqrtf(dg);
            float n1 = 1.0f / dg;
            #pragma unroll
            for (int ct = 0; ct < 8; ct++) {
                int j = ct * 16 + row16;
                float o = 0.5f * nrm * acc[mt][ct][r]
                        + 0.5f * n1 * init[(size_t)m * DIM + j]
                        + 0.5f * feat[(size_t)m * DIM + j];
                out[(size_t)m * DIM + j] = fmaxf(o, 0.f);
            }
        }
    }
}

extern "C" void kernel_launch(void* const* d_in, const int* in_sizes, int n_in,
                              void* d_out, int out_size, void* d_ws, size_t ws_size,
                              hipStream_t stream) {
    const float* feat = (const float*)d_in[0];
    const float* init = (const float*)d_in[1];
    const float* W    = (const float*)d_in[2];
    const int*   src  = (const int*)d_in[3];
    const int*   dst  = (const int*)d_in[4];
    const int N = in_sizes[0] / DIM;
    const int E = in_sizes[3];
    float* out = (float*)d_out;

    char* ws = (char*)d_ws;
    size_t o_deg = 0;
    size_t o_bs  = o_deg + (size_t)N * 4;
    size_t o_off = o_bs + 2048;
    size_t o_srt = (o_off + (size_t)(N + 1) * 4 + 127) & ~(size_t)127;
    size_t o_fs  = (o_srt + (size_t)E * 4 + 511) & ~(size_t)511;
    size_t o_agg = o_fs + (size_t)N * DIM * 2;
    size_t o_w   = o_agg + (size_t)N * DIM * 2;
    int*            deg        = (int*)(ws + o_deg);   // later reused as cursor
    int*            bsums      = (int*)(ws + o_bs);
    int*            offsets    = (int*)(ws + o_off);
    int*            sorted_src = (int*)(ws + o_srt);
    unsigned short* feat_s     = (unsigned short*)(ws + o_fs);
    unsigned short* agg        = (unsigned short*)(ws + o_agg);
    unsigned short* wb         = (unsigned short*)(ws + o_w);

    const int nb = (N + 255) / 256;
    const int eb = (E + 255) / 256;
    const int npp = (N + 7) / 8;          // nodes per XCD partition

    hipMemsetAsync(ws, 0, o_off, stream);                         // deg + bsums
    count_deg_k<<<eb, 256, 0, stream>>>(dst, deg, E);
    block_sums_k<<<nb, 256, 0, stream>>>(deg, bsums, N);
    scan_bsums_k<<<1, 512, 0, stream>>>(bsums, nb, offsets, N);
    scan_write_k<<<nb, 256, 0, stream>>>(deg, bsums, offsets, N);
    hipMemsetAsync(deg, 0, (size_t)N * 4, stream);                // reuse as cursor
    fill_sorted_xcd_k<<<2048, 256, 0, stream>>>(src, dst, offsets, deg, sorted_src, E, npp);

    prep_w_k<<<(DIM * DIM + 255) / 256, 256, 0, stream>>>(W, wb);
    prescale_k<<<(N * (DIM / 4) + 255) / 256, 256, 0, stream>>>(feat, offsets, feat_s, N);
    aggregate_k<<<(int)(((size_t)N * 64 + 255) / 256), 256, 0, stream>>>(
        feat_s, offsets, sorted_src, agg, N);
    gemm_ep_k<<<(N + 127) / 128, 256, 0, stream>>>(agg, wb, offsets, feat, init, out, N);
}